// Round 1
// 922.371 us; speedup vs baseline: 1.3432x; 1.3432x over previous
//
#include <hip/hip_runtime.h>
#include <stdint.h>

// MaxUnpooling2D scatter-add, two-pass binning with COALESCED pair writes.
//
// Evidence (R0 rocprof): bin_pairs WRITE_SIZE = 962 MB vs 268 MB useful
// (3.6x write amplification from scattered 8B writes evicted as partial
// 64B lines; per-XCD write set 32MB >> 4MB L2). VALUBusy 2% => memory-pipe
// backpressure, not BW. Fix: LDS-stage a 16K-element sub-chunk, bucket-sort
// locally, pad runs to 32B, write contiguous full lines.
//
// B=8, per-batch in = 2^22 elems, per-batch out = 2^24 floats.
// Region = 2^15 floats (128 KiB pass-2 LDS tile). 512 buckets/batch, 4096 total.

#define LOG2_REGION 15
#define REGION      (1 << LOG2_REGION)            // 32768 floats
#define NB          (1 << (24 - LOG2_REGION))     // 512 buckets per batch
#define NBUCKETS    (8 * NB)                      // 4096
#define SUB         16384                         // elements per pass-1 block
#define BLOCK1      1024
#define GRID1       ((1 << 25) / SUB)             // 2048 blocks
#define PADM        3                             // pad runs to 4 pairs (32 B)
#define STAGE_CAP   (SUB + PADM * NB)             // 17920 pairs = 140 KiB
#define BLOCK2      1024

// ---------------- Pass 1: LDS bucket-sort sub-chunk, coalesced run writes --
__global__ __launch_bounds__(BLOCK1) void bin_pairs(
    const int*   __restrict__ idx,
    const float* __restrict__ val,
    int*         __restrict__ counters,   // [NBUCKETS], pre-zeroed (padded counts)
    uint64_t*    __restrict__ pairs,      // [NBUCKETS * cap]
    int cap)
{
    __shared__ uint64_t stage[STAGE_CAP];  // 143,360 B
    __shared__ int hist[NB];               // raw counts
    __shared__ int pos[NB];                // scan buf -> lstart -> cursor
    __shared__ int gseg[NB];               // global segment base (multiple of 4)
    __shared__ int s_total;

    const int tid = threadIdx.x;
    const long long start = (long long)blockIdx.x * SUB;   // within one batch
    const int batch = (int)(start >> 22);
    const int4*   idx4 = (const int4*)(idx + start);
    const float4* val4 = (const float4*)(val + start);

    for (int i = tid; i < NB; i += BLOCK1) hist[i] = 0;
    __syncthreads();

    // phase 1: load indices (kept in regs), histogram
    int4 iv[4];
    #pragma unroll
    for (int it = 0; it < 4; ++it) {
        iv[it] = idx4[it * BLOCK1 + tid];
        atomicAdd(&hist[iv[it].x >> LOG2_REGION], 1);
        atomicAdd(&hist[iv[it].y >> LOG2_REGION], 1);
        atomicAdd(&hist[iv[it].z >> LOG2_REGION], 1);
        atomicAdd(&hist[iv[it].w >> LOG2_REGION], 1);
    }
    __syncthreads();

    // phase 2: inclusive scan of padded counts (Hillis-Steele over 512)
    if (tid < NB) pos[tid] = (hist[tid] + PADM) & ~PADM;
    __syncthreads();
    for (int off = 1; off < NB; off <<= 1) {
        int v = 0;
        if (tid < NB && tid >= off) v = pos[tid - off];
        __syncthreads();
        if (tid < NB && tid >= off) pos[tid] += v;
        __syncthreads();
    }
    if (tid == NB - 1) s_total = pos[tid];
    int excl = 0, hp = 0;
    if (tid < NB) { hp = (hist[tid] + PADM) & ~PADM; excl = pos[tid] - hp; }
    __syncthreads();
    if (tid < NB) {
        pos[tid] = excl;                                   // lstart (mult of 4)
        int* gc = counters + batch * NB;
        gseg[tid] = hp ? atomicAdd(&gc[tid], hp) : 0;      // mult of 4
    }
    __syncthreads();

    // phase 3: scatter pairs into LDS stage (bucket-sorted)
    #pragma unroll
    for (int it = 0; it < 4; ++it) {
        float4 vv = val4[it * BLOCK1 + tid];
        int   ia[4] = {iv[it].x, iv[it].y, iv[it].z, iv[it].w};
        float fa[4] = {vv.x, vv.y, vv.z, vv.w};
        #pragma unroll
        for (int k = 0; k < 4; ++k) {
            int b = ia[k] >> LOG2_REGION;
            int l = atomicAdd(&pos[b], 1);
            stage[l] = (uint64_t)(uint32_t)ia[k]
                     | ((uint64_t)__float_as_uint(fa[k]) << 32);
        }
    }
    __syncthreads();

    // phase 4: pad runs with harmless zero-adds (bucket b, offset 0, val 0.0f)
    for (int b = tid; b < NB; b += BLOCK1) {
        int h = hist[b];
        int hp2 = (h + PADM) & ~PADM;
        int st = pos[b];                                   // == lstart + h
        for (int j = 0; j < hp2 - h; ++j)
            stage[st + j] = (uint64_t)(uint32_t)(b << LOG2_REGION);
    }
    __syncthreads();

    // phase 5: contiguous, 32B-aligned run copy to global segments
    const int total = s_total;
    uint64_t* pb = pairs + (uint64_t)batch * NB * (uint64_t)cap;
    for (int i = tid; i < total; i += BLOCK1) {
        uint64_t p = stage[i];
        int b = (int)((uint32_t)p >> LOG2_REGION);
        int lstart_b = pos[b] - hist[b];
        int dst = gseg[b] + (i - lstart_b);
        if (dst < cap)
            pb[(uint64_t)b * cap + dst] = p;
    }
}

// ---------------- Pass 2: per-bucket LDS accumulate + coalesced write ------
__global__ __launch_bounds__(BLOCK2) void accumulate(
    const uint64_t* __restrict__ pairs,
    const int*      __restrict__ counters,
    float*          __restrict__ out,
    int cap)
{
    __shared__ float acc[REGION];          // 128 KiB
    const int b = blockIdx.x;              // bucket id == output region id
    const int tid = threadIdx.x;

    float4* acc4 = (float4*)acc;
    for (int i = tid; i < REGION / 4; i += BLOCK2)
        acc4[i] = make_float4(0.f, 0.f, 0.f, 0.f);
    __syncthreads();

    int n = counters[b];
    if (n > cap) n = cap;
    const uint64_t* p = pairs + (uint64_t)b * cap;
    for (int i = tid; i < n; i += BLOCK2) {
        uint64_t v = p[i];
        atomicAdd(&acc[(int)(v & (REGION - 1))],
                  __uint_as_float((uint32_t)(v >> 32)));   // ds_add_f32
    }
    __syncthreads();

    // out offset: batch*2^24 + region*2^15 == b * 2^15  (b = batch*512+region)
    float4* o4 = (float4*)(out + ((long long)b << LOG2_REGION));
    for (int i = tid; i < REGION / 4; i += BLOCK2)
        o4[i] = acc4[i];
}

extern "C" void kernel_launch(void* const* d_in, const int* in_sizes, int n_in,
                              void* d_out, int out_size, void* d_ws, size_t ws_size,
                              hipStream_t stream) {
    const float* in  = (const float*)d_in[0];
    const int*   idx = (const int*)d_in[1];
    float*       out = (float*)d_out;

    int*      counters = (int*)d_ws;
    uint64_t* pairs    = (uint64_t*)((char*)d_ws + 65536);

    // capacity per bucket (pairs), bounded by workspace; keep multiple of 4.
    // Expected padded pairs/bucket = 2^22/512 + pads ~ 8.6K; cap 16K is safe.
    int cap = (int)(((ws_size - 65536) / 8) / NBUCKETS);
    if (cap > 16384) cap = 16384;
    cap &= ~PADM;

    hipMemsetAsync(counters, 0, NBUCKETS * sizeof(int), stream);
    bin_pairs<<<GRID1, BLOCK1, 0, stream>>>(idx, in, counters, pairs, cap);
    accumulate<<<NBUCKETS, BLOCK2, 0, stream>>>(pairs, counters, out, cap);
}